// Round 7
// baseline (1337.971 us; speedup 1.0000x reference)
//
#include <hip/hip_runtime.h>
#include <hip/hip_cooperative_groups.h>
#include <math.h>

namespace cg = cooperative_groups;

// ---------------------------------------------------------------------------
// GCN forward: 3x GCNConv (sym-norm, self-loops) + linear + global max pool.
// N=50000, E=800000, F=256, H=128, O=64. fp32 in/out, fp16 intermediates.
//
// R16 = R15 structure (algebraic reassociation: one GEMM + three 64-wide
// 1-line/edge gathers at the ~40G line-requests/s plateau) with the launch
// count cut 17 -> 5. R15's kernels were all <41us; ~140us was inter-launch
// gaps. Now: {k_hist, k_scanC(coop), k_part, k_build, k_mega(coop)}.
// k_mega is a persistent cooperative kernel: weight chain -> pack -> cvec/
// gmax-init -> GEMM -> hop1||u1 -> hop2||u2 -> hop3+pool -> decode, with
// grid.sync() between phases. Buffers are write-once-read-once per phase
// (tmpY->tmpZ->tmpW) so only release/acquire at the sync is needed (no
// stale-L1 WAR hazard across XCD L2s).
// ---------------------------------------------------------------------------

typedef __attribute__((ext_vector_type(8))) _Float16 f16x8;
typedef __attribute__((ext_vector_type(4))) _Float16 f16x4;
typedef __attribute__((ext_vector_type(4))) float f32x4;

__device__ __forceinline__ unsigned enc_f32(float f) {
    unsigned u = __float_as_uint(f);
    return (u & 0x80000000u) ? ~u : (u | 0x80000000u);
}
__device__ __forceinline__ float dec_f32(unsigned e) {
    return (e & 0x80000000u) ? __uint_as_float(e & 0x7fffffffu)
                             : __uint_as_float(~e);
}
#define ENC_NEG_INF 0x007FFFFFu  // enc(-inf)
#define MEGA_LDS 35072           // 32KB Bs + 2KB As (mm2) >= 24KB gemm tile

// ------------------------------------------------------- graph build, pass A
__global__ __launch_bounds__(256) void k_hist(const int* __restrict__ dst,
                                              int* __restrict__ T,
                                              int E, int NB, int chunk) {
    __shared__ int hist[512];
    for (int i = threadIdx.x; i < 512; i += 256) hist[i] = 0;
    __syncthreads();
    const int lo = blockIdx.x * chunk, hi = min(E, lo + chunk);
    for (int e = lo + threadIdx.x; e < hi; e += 256)
        atomicAdd(&hist[dst[e] >> 7], 1);
    __syncthreads();
    for (int b = threadIdx.x; b < NB; b += 256)
        T[b * 256 + blockIdx.x] = hist[b];
}

// --------------------------------------------- cooperative 3-phase scan
// excl = exclusive scan of in[L]; bsums used as scratch (block sums -> block
// offsets in place). Launch cooperatively with gridDim = L/1024.
__global__ __launch_bounds__(1024) void k_scanC(const int* __restrict__ in,
                                                int* __restrict__ excl,
                                                int* __restrict__ bsums, int L) {
    cg::grid_group grid = cg::this_grid();
    __shared__ int sh[1024];
    const int t = threadIdx.x;
    {
        int i = blockIdx.x * 1024 + t;
        int v = (i < L) ? in[i] : 0;
        sh[t] = v;
        __syncthreads();
        for (int off = 1; off < 1024; off <<= 1) {
            int tv = (t >= off) ? sh[t - off] : 0;
            __syncthreads();
            sh[t] += tv;
            __syncthreads();
        }
        if (i < L) excl[i] = sh[t] - v;
        if (t == 1023) bsums[blockIdx.x] = sh[1023];
    }
    __threadfence();
    grid.sync();
    if (blockIdx.x == 0) {
        int nb = (int)gridDim.x;
        int v = (t < nb) ? bsums[t] : 0;
        sh[t] = v;
        __syncthreads();
        for (int off = 1; off < 1024; off <<= 1) {
            int tv = (t >= off) ? sh[t - off] : 0;
            __syncthreads();
            sh[t] += tv;
            __syncthreads();
        }
        if (t < nb) bsums[t] = sh[t] - v;
        __threadfence();
    }
    grid.sync();
    {
        int i = blockIdx.x * 1024 + t;
        if (i < L) excl[i] += bsums[i >> 10];
    }
}

// ------------------------------------------------------- graph build, pass B
#define PBT 4096
__global__ __launch_bounds__(256) void k_part(const int* __restrict__ src,
                                              const int* __restrict__ dst,
                                              const int* __restrict__ T2,
                                              unsigned* __restrict__ eb,
                                              int E, int NB, int chunk) {
    __shared__ int hist[512], lexc[512], pos[512], wpos[512];
    __shared__ unsigned sorted[PBT];
    const int t = threadIdx.x;
    const int blk = blockIdx.x;
    const int lo = blk * chunk, hi = min(E, lo + chunk);
    for (int i = t; i < NB; i += 256) wpos[i] = T2[i * 256 + blk];
    __syncthreads();
    for (int tlo = lo; tlo < hi; tlo += PBT) {
        const int thi = min(hi, tlo + PBT);
        const int sz = thi - tlo;
        for (int i = t; i < 512; i += 256) hist[i] = 0;
        __syncthreads();
        for (int e = tlo + t; e < thi; e += 256)
            atomicAdd(&hist[dst[e] >> 7], 1);
        __syncthreads();
        const int i0 = t, i1 = t + 256;
        const int o0 = hist[i0], o1 = hist[i1];
        for (int off = 1; off < 512; off <<= 1) {
            int v0 = (i0 >= off) ? hist[i0 - off] : 0;
            int v1 = (i1 >= off) ? hist[i1 - off] : 0;
            __syncthreads();
            hist[i0] += v0;
            hist[i1] += v1;
            __syncthreads();
        }
        lexc[i0] = hist[i0] - o0; pos[i0] = hist[i0] - o0;
        lexc[i1] = hist[i1] - o1; pos[i1] = hist[i1] - o1;
        __syncthreads();
        for (int e = tlo + t; e < thi; e += 256) {
            int d = dst[e];
            int p = atomicAdd(&pos[d >> 7], 1);
            sorted[p] = ((unsigned)d << 16) | (unsigned)src[e];
        }
        __syncthreads();
        for (int i = t; i < sz; i += 256) {
            unsigned x = sorted[i];
            int b = (int)(x >> 23);
            eb[wpos[b] + (i - lexc[b])] = x;
        }
        __syncthreads();
        wpos[i0] += o0;
        wpos[i1] += o1;
        __syncthreads();
    }
}

// ------------------------------------------------------- graph build, pass C
#define PCT 6144
__global__ __launch_bounds__(256) void k_build(const unsigned* __restrict__ eb,
                                               const int* __restrict__ T2,
                                               unsigned short* __restrict__ csr,
                                               int* __restrict__ rofs,
                                               float* __restrict__ dinv,
                                               int N, int E, int NB) {
    __shared__ int hist[128], lofs[128], pos[128];
    __shared__ unsigned short ssrc[PCT];
    const int t = threadIdx.x;
    const int b = blockIdx.x;
    const int glo = T2[b * 256];
    const int ghi = (b + 1 < NB) ? T2[(b + 1) * 256] : E;
    const int sz = ghi - glo;
    if (t < 128) hist[t] = 0;
    __syncthreads();
    for (int i = t; i < sz; i += 256)
        atomicAdd(&hist[(eb[glo + i] >> 16) & 127], 1);
    __syncthreads();
    const int o = (t < 128) ? hist[t] : 0;
    for (int off = 1; off < 128; off <<= 1) {
        int v = (t < 128 && t >= off) ? hist[t - off] : 0;
        __syncthreads();
        if (t < 128) hist[t] += v;
        __syncthreads();
    }
    if (t < 128) {
        int ex = hist[t] - o;
        lofs[t] = ex;
        pos[t] = ex;
        int d = b * 128 + t;
        if (d < N) {
            rofs[d] = glo + ex;
            dinv[d] = rsqrtf((float)(o + 1));
        }
    }
    __syncthreads();
    if (sz <= PCT) {
        for (int i = t; i < sz; i += 256) {
            unsigned x = eb[glo + i];
            int p = atomicAdd(&pos[(x >> 16) & 127], 1);
            ssrc[p] = (unsigned short)(x & 0xFFFFu);
        }
        __syncthreads();
        for (int i = t; i < sz; i += 256) csr[glo + i] = ssrc[i];
    } else {
        for (int i = t; i < sz; i += 256) {
            unsigned x = eb[glo + i];
            int p = atomicAdd(&pos[(x >> 16) & 127], 1);
            csr[glo + p] = (unsigned short)(x & 0xFFFFu);
        }
    }
    if (b == 0 && t == 0) rofs[N] = E;
}

// ============================ mega-kernel device phases =====================

// tiny latency-optimal GEMM tile: C[vb*4..+3][64] = A * B, B(128x64) in LDS.
__device__ __forceinline__ void mm2_dev(const float* __restrict__ A,
                                        const float* __restrict__ B,
                                        float* __restrict__ C,
                                        _Float16* __restrict__ Wp,
                                        int pack, int vb, int tid, char* smemc) {
    float* Bs = (float*)smemc;          // 32 KB
    float* As = (float*)(smemc + 32768); // 2 KB
    const int r0 = vb * 4;
    __syncthreads();
#pragma unroll
    for (int it = 0; it < 8; ++it) {
        int f = tid + it * 256;
        *(float4*)&Bs[f * 4] = *(const float4*)&B[(size_t)f * 4];
    }
    if (tid < 128)
        *(float4*)&As[tid * 4] = *(const float4*)&A[(size_t)r0 * 128 + tid * 4];
    __syncthreads();
    const int n = tid & 63;
    const int rh = tid >> 6;
    float a0 = 0.f, a1 = 0.f, a2 = 0.f, a3 = 0.f;
#pragma unroll
    for (int k = 0; k < 128; k += 4) {
        a0 = fmaf(As[rh * 128 + k + 0], Bs[(k + 0) * 64 + n], a0);
        a1 = fmaf(As[rh * 128 + k + 1], Bs[(k + 1) * 64 + n], a1);
        a2 = fmaf(As[rh * 128 + k + 2], Bs[(k + 2) * 64 + n], a2);
        a3 = fmaf(As[rh * 128 + k + 3], Bs[(k + 3) * 64 + n], a3);
    }
    float acc = (a0 + a1) + (a2 + a3);
    const int kk = r0 + rh;
    if (pack) {
        int j = kk & 7;
        int l = ((kk >> 3) & 3) * 16 + (n & 15);
        int q = kk >> 5;
        int c = n >> 4;
        Wp[((size_t)(c * 8 + q) * 64 + l) * 8 + j] = (_Float16)acc;
    } else {
        C[(size_t)kk * 64 + n] = acc;
    }
}

__device__ __forceinline__ void cvec_dev(const float* __restrict__ b0,
                                         const float* __restrict__ b1,
                                         const float* __restrict__ b2,
                                         const float* __restrict__ blin,
                                         const float* __restrict__ P,
                                         const float* __restrict__ Q,
                                         const float* __restrict__ Wl,
                                         float* __restrict__ cv,
                                         int tid, char* smemc) {
    int* nzf = (int*)smemc;
    if (tid == 0) *nzf = 0;
    __syncthreads();
    const int v = tid >> 6;
    const int n = tid & 63;
    if (v < 3) {
        const float* bb = (v == 0) ? b0 : (v == 1) ? b1 : b2;
        const float* M = (v == 0) ? P : (v == 1) ? Q : Wl;
        float a0 = 0.f, a1 = 0.f, a2 = 0.f, a3 = 0.f;
#pragma unroll
        for (int k = 0; k < 128; k += 4) {
            a0 = fmaf(bb[k + 0], M[(k + 0) * 64 + n], a0);
            a1 = fmaf(bb[k + 1], M[(k + 1) * 64 + n], a1);
            a2 = fmaf(bb[k + 2], M[(k + 2) * 64 + n], a2);
            a3 = fmaf(bb[k + 3], M[(k + 3) * 64 + n], a3);
        }
        float c = (a0 + a1) + (a2 + a3);
        if (v == 2) c += blin[n];
        cv[v * 64 + n] = c;
        if (v < 2 && c != 0.f) atomicOr(nzf, 1);
    }
    __syncthreads();
    if (tid == 0) cv[192] = (*nzf) ? 1.f : 0.f;
}

// MFMA GEMM tile: rows vb*96..+95, Y = (dinv .* (X * W0123)) as fp16 [N][64].
__device__ __forceinline__ void gemm_dev(const float* __restrict__ A,
                                         const _Float16* __restrict__ Wp,
                                         const float* __restrict__ sc,
                                         _Float16* __restrict__ outp,
                                         int N, int vb, int tid, char* smemc) {
    constexpr int KB = 128, NQ = 2, NK = 4, KG = 16, CT = 2, RT = 3;
    _Float16* As = (_Float16*)smemc;   // 24 KB
    const int lane = tid & 63;
    const int wave = tid >> 6;
    const int wrow = wave >> 1;
    const int wcol = wave & 1;
    const int R0 = vb * 96;

    f32x4 acc[RT][CT];
#pragma unroll
    for (int rt = 0; rt < RT; ++rt)
#pragma unroll
        for (int ct = 0; ct < CT; ++ct) acc[rt][ct] = (f32x4){0.f, 0.f, 0.f, 0.f};

    for (int q = 0; q < NQ; ++q) {
        __syncthreads();
#pragma unroll
        for (int it = 0; it < 12; ++it) {  // 96*128/(4*256)
            int idx = tid + it * 256;
            int r = idx >> 5;
            int f4 = idx & 31;
            float4 g = {0.f, 0.f, 0.f, 0.f};
            if (R0 + r < N) g = *(const float4*)&A[(size_t)(R0 + r) * 256 + q * KB + f4 * 4];
            int kg = f4 >> 1, sub = f4 & 1;
            f16x4 h;
            h[0] = (_Float16)g.x; h[1] = (_Float16)g.y;
            h[2] = (_Float16)g.z; h[3] = (_Float16)g.w;
            *(f16x4*)&As[(r >> 4) * (KG * 128) + kg * 128 + (((r & 15) ^ kg) * 8) + sub * 4] = h;
        }
        __syncthreads();
#pragma unroll
        for (int qq = 0; qq < NK; ++qq) {
            const int kk = q * NK + qq;
            const int kgq = qq * 4 + (lane >> 4);
            f16x8 af[RT], bf[CT];
#pragma unroll
            for (int ct = 0; ct < CT; ++ct) {
                int t = wcol * CT + ct;
                bf[ct] = *(const f16x8*)&Wp[((size_t)(t * 8 + kk) * 64 + lane) * 8];
            }
#pragma unroll
            for (int rt = 0; rt < RT; ++rt) {
                int tr = wrow * RT + rt;
                af[rt] = *(const f16x8*)&As[tr * (KG * 128) + kgq * 128 + (((lane & 15) ^ kgq) * 8)];
            }
#pragma unroll
            for (int rt = 0; rt < RT; ++rt)
#pragma unroll
                for (int ct = 0; ct < CT; ++ct)
                    acc[rt][ct] = __builtin_amdgcn_mfma_f32_16x16x32_f16(af[rt], bf[ct], acc[rt][ct], 0, 0, 0);
        }
    }

    const int quad = lane >> 4;
#pragma unroll
    for (int rt = 0; rt < RT; ++rt)
#pragma unroll
        for (int reg = 0; reg < 4; ++reg) {
            int r = R0 + wrow * 48 + rt * 16 + quad * 4 + reg;
            if (r < N) {
                float s = sc[r];
#pragma unroll
                for (int ct = 0; ct < CT; ++ct) {
                    int c = wcol * (CT * 16) + ct * 16 + (lane & 15);
                    outp[(size_t)r * 64 + c] = (_Float16)(acc[rt][ct][reg] * s);
                }
            }
        }
}

// 64-wide aggregation quad (4 rows/block-iteration). FIN=1: bias terms +
// atomicMax into gmax.
template <int FIN>
__device__ __forceinline__ void agg_dev(const _Float16* __restrict__ tmp,
                                        const float* __restrict__ dinv,
                                        const int* __restrict__ rofs,
                                        const unsigned short* __restrict__ csr,
                                        const float* __restrict__ u1,
                                        const float* __restrict__ u2,
                                        const float* __restrict__ cv,
                                        _Float16* __restrict__ outp,
                                        unsigned* __restrict__ gmax,
                                        int N, int vb, int tid, char* smemc) {
    unsigned* smax = (unsigned*)smemc;
    const int lane = tid & 63;
    const int wave = tid >> 6;
    const int d = vb * 4 + wave;
    const int eh = lane >> 3;   // edge slot 0..7
    const int fl = lane & 7;    // feature octet 0..7
    if (FIN) {
        if (tid < 64) smax[tid] = ENC_NEG_INF;
        __syncthreads();
    }
    if (d < N) {
        const int beg = rofs[d], end = rofs[d + 1];
        float a[8];
#pragma unroll
        for (int j = 0; j < 8; ++j) a[j] = 0.f;
        f16x8 vd;
        if (eh == 7) vd = *(const f16x8*)&tmp[(size_t)d * 64 + fl * 8];
        for (int base = beg; base < end; base += 32) {
            f16x8 v[4];
            unsigned msk = 0;
#pragma unroll
            for (int i = 0; i < 4; ++i) {
                int idx = base + 8 * i + eh;
                if (idx < end) {
                    int s = csr[idx];
                    v[i] = *(const f16x8*)&tmp[(size_t)s * 64 + fl * 8];
                    msk |= 1u << i;
                }
            }
#pragma unroll
            for (int i = 0; i < 4; ++i)
                if (msk & (1u << i)) {
#pragma unroll
                    for (int j = 0; j < 8; ++j) a[j] += (float)v[i][j];
                }
        }
        if (eh == 7) {
#pragma unroll
            for (int j = 0; j < 8; ++j) a[j] += (float)vd[j];
        }
#pragma unroll
        for (int j = 0; j < 8; ++j) {
            a[j] += __shfl_xor(a[j], 8, 64);
            a[j] += __shfl_xor(a[j], 16, 64);
            a[j] += __shfl_xor(a[j], 32, 64);
        }
        if (FIN == 0) {
            if (eh == 0) {
                float di = dinv[d];
                float s2 = di * di;
                f16x8 o;
#pragma unroll
                for (int j = 0; j < 8; ++j) o[j] = (_Float16)(a[j] * s2);
                *(f16x8*)&outp[(size_t)d * 64 + fl * 8] = o;
            }
        } else {
            if (eh == 0) {
                float di = dinv[d];
                float v1 = u1[d], v2 = u2[d];
#pragma unroll
                for (int j = 0; j < 8; ++j) {
                    int f = fl * 8 + j;
                    float z = fmaf(di, a[j],
                              fmaf(v2, cv[f], fmaf(v1, cv[64 + f], cv[128 + f])));
                    atomicMax(&smax[f], enc_f32(z));
                }
            }
        }
    }
    if (FIN) {
        __syncthreads();
        if (tid < 64) atomicMax(&gmax[tid], smax[tid]);
    }
}

__device__ __forceinline__ void u1_dev(const float* __restrict__ dinv,
                                       const int* __restrict__ rofs,
                                       const unsigned short* __restrict__ csr,
                                       const float* __restrict__ cv,
                                       float* __restrict__ u1,
                                       float* __restrict__ w1, int N,
                                       int vb, int tid) {
    int d = vb * 256 + tid;
    if (d >= N) return;
    if (cv[192] == 0.f) { u1[d] = 0.f; w1[d] = 0.f; return; }
    float s = 0.f;
    const int beg = rofs[d], end = rofs[d + 1];
    for (int e = beg; e < end; ++e) s += dinv[csr[e]];
    float di = dinv[d];
    float u = di * (s + di);
    u1[d] = u;
    w1[d] = di * u;
}

__device__ __forceinline__ void u2_dev(const float* __restrict__ dinv,
                                       const int* __restrict__ rofs,
                                       const unsigned short* __restrict__ csr,
                                       const float* __restrict__ cv,
                                       const float* __restrict__ w1,
                                       float* __restrict__ u2, int N,
                                       int vb, int tid) {
    int d = vb * 256 + tid;
    if (d >= N) return;
    if (cv[192] == 0.f) { u2[d] = 0.f; return; }
    float s = 0.f;
    const int beg = rofs[d], end = rofs[d + 1];
    for (int e = beg; e < end; ++e) s += w1[csr[e]];
    u2[d] = dinv[d] * (s + w1[d]);
}

// ----------------------------------------------- the cooperative mega-kernel
__global__ __launch_bounds__(256, 4) void k_mega(
    const float* W0, const float* W1, const float* W2, const float* Wl,
    const float* b0, const float* b1, const float* b2, const float* blin,
    const float* x, const float* dinv, const int* rofs,
    const unsigned short* csr,
    float* Q, float* P, float* cv, _Float16* wp,
    _Float16* tmpY, _Float16* tmpZ, _Float16* tmpW,
    float* u1, float* w1, float* u2, unsigned* gmax, float* outp, int N) {
    cg::grid_group grid = cg::this_grid();
    __shared__ char smem[MEGA_LDS];
    const int tid = threadIdx.x;
    const int nbG = (N + 95) / 96;
    const int nbAg = (N + 3) / 4;
    const int nbU = (N + 255) / 256;

    // P0: Q = W2 * Wl
    for (int vb = blockIdx.x; vb < 32; vb += gridDim.x)
        mm2_dev(W2, Wl, Q, nullptr, 0, vb, tid, smem);
    __threadfence(); grid.sync();
    // P1: P = W1 * Q
    for (int vb = blockIdx.x; vb < 32; vb += gridDim.x)
        mm2_dev(W1, Q, P, nullptr, 0, vb, tid, smem);
    __threadfence(); grid.sync();
    // P2: wp = pack(W0 * P) | cvec | gmax init
    for (int vb = blockIdx.x; vb < 66; vb += gridDim.x) {
        if (vb < 64) mm2_dev(W0, P, nullptr, wp, 1, vb, tid, smem);
        else if (vb == 64) cvec_dev(b0, b1, b2, blin, P, Q, Wl, cv, tid, smem);
        else if (tid < 64) gmax[tid] = ENC_NEG_INF;
    }
    __threadfence(); grid.sync();
    // PG: Y = dinv .* (X * W0123)
    for (int vb = blockIdx.x; vb < nbG; vb += gridDim.x)
        gemm_dev(x, wp, dinv, tmpY, N, vb, tid, smem);
    __threadfence(); grid.sync();
    // H1: hop1 (tmpY -> tmpZ) || u1
    for (int vb = blockIdx.x; vb < nbAg + nbU; vb += gridDim.x) {
        if (vb < nbAg)
            agg_dev<0>(tmpY, dinv, rofs, csr, nullptr, nullptr, nullptr,
                       tmpZ, nullptr, N, vb, tid, smem);
        else
            u1_dev(dinv, rofs, csr, cv, u1, w1, N, vb - nbAg, tid);
    }
    __threadfence(); grid.sync();
    // H2: hop2 (tmpZ -> tmpW) || u2
    for (int vb = blockIdx.x; vb < nbAg + nbU; vb += gridDim.x) {
        if (vb < nbAg)
            agg_dev<0>(tmpZ, dinv, rofs, csr, nullptr, nullptr, nullptr,
                       tmpW, nullptr, N, vb, tid, smem);
        else
            u2_dev(dinv, rofs, csr, cv, w1, u2, N, vb - nbAg, tid);
    }
    __threadfence(); grid.sync();
    // H3: hop3 + bias + global max
    for (int vb = blockIdx.x; vb < nbAg; vb += gridDim.x)
        agg_dev<1>(tmpW, dinv, rofs, csr, u1, u2, cv, nullptr, gmax,
                   N, vb, tid, smem);
    __threadfence(); grid.sync();
    // decode
    if (blockIdx.x == 0 && tid < 64) outp[tid] = dec_f32(gmax[tid]);
}

// ---------------------------------------------------------------------------
extern "C" void kernel_launch(void* const* d_in, const int* in_sizes, int n_in,
                              void* d_out, int out_size, void* d_ws, size_t ws_size,
                              hipStream_t stream) {
    const float* x    = (const float*)d_in[0];
    const int*   ei   = (const int*)d_in[1];  // [2,E]: row0=src, row1=dst
    const float* W0   = (const float*)d_in[3];
    const float* b0   = (const float*)d_in[4];
    const float* W1   = (const float*)d_in[5];
    const float* b1   = (const float*)d_in[6];
    const float* W2   = (const float*)d_in[7];
    const float* b2   = (const float*)d_in[8];
    const float* Wlin = (const float*)d_in[9];
    const float* blin = (const float*)d_in[10];
    float* out = (float*)d_out;

    const int N = in_sizes[2];
    const int E = in_sizes[1] / 2;
    const int* src = ei;
    const int* dst = ei + E;

    size_t off = 0;
    auto carve = [&](size_t bytes) {
        void* p = (char*)d_ws + off;
        off += (bytes + 255) & ~(size_t)255;
        return p;
    };
    const int NB    = (N + 127) / 128;
    const int L     = NB * 256;
    const int chunk = (E + 255) / 256;

    float*          dinv = (float*)carve((size_t)N * 4);
    int*            rofs = (int*)carve((size_t)(N + 1) * 4);
    int*            T    = (int*)carve((size_t)L * 4);
    int*            T2   = (int*)carve((size_t)L * 4);
    int*            bsums = (int*)carve(1024 * 4);
    unsigned*       eb   = (unsigned*)carve((size_t)E * 4);
    unsigned short* csr  = (unsigned short*)carve((size_t)E * 2);
    _Float16*       tmpY = (_Float16*)carve((size_t)N * 64 * 2);
    _Float16*       tmpZ = (_Float16*)carve((size_t)N * 64 * 2);
    _Float16*       tmpW = (_Float16*)carve((size_t)N * 64 * 2);
    float*          u1   = (float*)carve((size_t)N * 4);
    float*          w1   = (float*)carve((size_t)N * 4);
    float*          u2   = (float*)carve((size_t)N * 4);
    float*          Q    = (float*)carve(128 * 64 * 4);
    float*          P    = (float*)carve(128 * 64 * 4);
    float*          cv   = (float*)carve(256 * 4);
    _Float16*       wp   = (_Float16*)carve(256 * 64 * 2);
    unsigned*       gmax = (unsigned*)carve(64 * 4);
    (void)ws_size; (void)n_in; (void)out_size;

    const int nbS = (L + 1023) / 1024;

    // graph build: hist -> coop scan -> partition -> per-bucket counting sort
    k_hist<<<256, 256, 0, stream>>>(dst, T, E, NB, chunk);
    {
        const int* in_p = T;
        int* ex_p = T2;
        int* bs_p = bsums;
        int Lv = L;
        void* sargs[] = {&in_p, &ex_p, &bs_p, &Lv};
        hipLaunchCooperativeKernel((const void*)k_scanC, dim3(nbS), dim3(1024),
                                   sargs, 0, stream);
    }
    k_part<<<256, 256, 0, stream>>>(src, dst, T2, eb, E, NB, chunk);
    k_build<<<NB, 256, 0, stream>>>(eb, T2, csr, rofs, dinv, N, E, NB);

    // cooperative mega-kernel: wchain -> pack/cvec -> gemm -> 3 hops -> pool
    static int megaGrid = 0;
    if (megaGrid == 0) {
        int perCU = 0;
        hipOccupancyMaxActiveBlocksPerMultiprocessor(&perCU, (const void*)k_mega,
                                                     256, 0);
        if (perCU < 1) perCU = 1;
        megaGrid = perCU * 256;
        if (megaGrid > 1024) megaGrid = 1024;
    }
    {
        const float *a0 = W0, *a1 = W1, *a2 = W2, *a3 = Wlin;
        const float *a4 = b0, *a5 = b1, *a6 = b2, *a7 = blin;
        const float *a8 = x, *a9 = dinv;
        const int* a10 = rofs;
        const unsigned short* a11 = csr;
        float *a12 = Q, *a13 = P, *a14 = cv;
        _Float16* a15 = wp;
        _Float16 *a16 = tmpY, *a17 = tmpZ, *a18 = tmpW;
        float *a19 = u1, *a20 = w1, *a21 = u2;
        unsigned* a22 = gmax;
        float* a23 = out;
        int a24 = N;
        void* margs[] = {&a0, &a1, &a2, &a3, &a4, &a5, &a6, &a7,
                         &a8, &a9, &a10, &a11, &a12, &a13, &a14, &a15,
                         &a16, &a17, &a18, &a19, &a20, &a21, &a22, &a23, &a24};
        hipLaunchCooperativeKernel((const void*)k_mega, dim3(megaGrid), dim3(256),
                                   margs, 0, stream);
    }
}

// Round 8
// 246.098 us; speedup vs baseline: 5.4367x; 5.4367x over previous
//
#include <hip/hip_runtime.h>
#include <math.h>

// ---------------------------------------------------------------------------
// GCN forward: 3x GCNConv (sym-norm, self-loops) + linear + global max pool.
// N=50000, E=800000, F=256, H=128, O=64. fp32 in/out, fp16 intermediates.
//
// R17 = R15 (best: 265us; algebraic reassociation Z = A^3 X (W0W1W2Wlin) +
// bias terms, one MFMA GEMM + three 64-wide 1-line/edge gathers at the
// ~40G line-requests/s plateau) with launch count cut 17 -> 10 by fusing
// INDEPENDENT jobs into shared ordinary dispatches (no grid.sync — R16's
// cooperative mega-kernel was 5x slower: persistent grid serialized the
// gather and grid.sync overhead dominated):
//  kA   = {W01=W0*W1 (2 halves), Q=W2*Wlin, hist}        (416 blocks)
//  scan1; scan23 (scan2 replicated per block + add)      (2 launches)
//  kP   = {part, wp=pack(W01*Q), cvec}                   (321 blocks)
//  build; gemm; agg1+u1; agg2+u2; agg3(FIN)->bmax; pool
// ---------------------------------------------------------------------------

typedef __attribute__((ext_vector_type(8))) _Float16 f16x8;
typedef __attribute__((ext_vector_type(4))) _Float16 f16x4;
typedef __attribute__((ext_vector_type(4))) float f32x4;

__device__ __forceinline__ unsigned enc_f32(float f) {
    unsigned u = __float_as_uint(f);
    return (u & 0x80000000u) ? ~u : (u | 0x80000000u);
}
__device__ __forceinline__ float dec_f32(unsigned e) {
    return (e & 0x80000000u) ? __uint_as_float(e & 0x7fffffffu)
                             : __uint_as_float(~e);
}
#define ENC_NEG_INF 0x007FFFFFu  // enc(-inf)

// --------------------------------------------- tiny latency-optimal GEMM tile
// Computes rows r0=vb*4..+3 of A[*][128] * B[128][64-col-slice].
// B staged in LDS (one latency round, 8 independent float4/thread), A rows
// staged by 128 threads. pack=1 writes fp16 MFMA-packed wp (K=256 layout).
__device__ __forceinline__ void mm2v_dev(const float* __restrict__ A,
                                         const float* __restrict__ B,
                                         int ldb, int bcol0,
                                         float* __restrict__ C,
                                         int ldc, int ccol0,
                                         _Float16* __restrict__ Wp, int pack,
                                         int vb, int tid,
                                         float* __restrict__ Bs,
                                         float* __restrict__ As) {
    const int r0 = vb * 4;
#pragma unroll
    for (int it = 0; it < 8; ++it) {
        int f = tid + it * 256;          // 2048 float4 slots: row = f>>4
        int row = f >> 4, c4 = (f & 15) * 4;
        *(float4*)&Bs[row * 64 + c4] = *(const float4*)&B[(size_t)row * ldb + bcol0 + c4];
    }
    if (tid < 128)
        *(float4*)&As[tid * 4] = *(const float4*)&A[(size_t)r0 * 128 + tid * 4];
    __syncthreads();
    const int n = tid & 63;
    const int rh = tid >> 6;
    float a0 = 0.f, a1 = 0.f, a2 = 0.f, a3 = 0.f;
#pragma unroll
    for (int k = 0; k < 128; k += 4) {
        a0 = fmaf(As[rh * 128 + k + 0], Bs[(k + 0) * 64 + n], a0);
        a1 = fmaf(As[rh * 128 + k + 1], Bs[(k + 1) * 64 + n], a1);
        a2 = fmaf(As[rh * 128 + k + 2], Bs[(k + 2) * 64 + n], a2);
        a3 = fmaf(As[rh * 128 + k + 3], Bs[(k + 3) * 64 + n], a3);
    }
    float acc = (a0 + a1) + (a2 + a3);
    const int kk = r0 + rh;
    if (pack) {
        int j = kk & 7;
        int l = ((kk >> 3) & 3) * 16 + (n & 15);
        int q = kk >> 5;
        int c = n >> 4;
        Wp[((size_t)(c * 8 + q) * 64 + l) * 8 + j] = (_Float16)acc;
    } else {
        C[(size_t)kk * ldc + ccol0 + n] = acc;
    }
}

// ------------------------------------- launch A: W01 halves + Q + histogram
// blocks 0..63: W01[:,0:64]=W0*W1[:,0:64]; 64..127: W01[:,64:128];
// 128..159: Q=W2*Wlin; 160..415: hist (256 chunks).
__global__ __launch_bounds__(256) void kA(const float* __restrict__ W0,
                                          const float* __restrict__ W1,
                                          const float* __restrict__ W2,
                                          const float* __restrict__ Wl,
                                          const int* __restrict__ dst,
                                          int* __restrict__ T,
                                          float* __restrict__ W01,
                                          float* __restrict__ Q,
                                          int E, int NB, int chunk) {
    __shared__ float Bs[128 * 64];
    __shared__ float As[4 * 128];
    __shared__ int hist[512];
    const int b = blockIdx.x;
    const int tid = threadIdx.x;
    if (b < 64) {
        mm2v_dev(W0, W1, 128, 0, W01, 128, 0, nullptr, 0, b, tid, Bs, As);
    } else if (b < 128) {
        mm2v_dev(W0, W1, 128, 64, W01, 128, 64, nullptr, 0, b - 64, tid, Bs, As);
    } else if (b < 160) {
        mm2v_dev(W2, Wl, 64, 0, Q, 64, 0, nullptr, 0, b - 128, tid, Bs, As);
    } else {
        const int blk = b - 160;
        for (int i = tid; i < 512; i += 256) hist[i] = 0;
        __syncthreads();
        const int lo = blk * chunk, hi = min(E, lo + chunk);
        for (int e = lo + tid; e < hi; e += 256)
            atomicAdd(&hist[dst[e] >> 7], 1);
        __syncthreads();
        for (int bk = tid; bk < NB; bk += 256)
            T[bk * 256 + blk] = hist[bk];
    }
}

// ------------------------------------------------------------- scan kernels
__global__ __launch_bounds__(1024) void k_scan1(const int* __restrict__ in,
                                                int* __restrict__ excl,
                                                int* __restrict__ bsums, int L) {
    __shared__ int sh[1024];
    int t = threadIdx.x;
    int i = blockIdx.x * 1024 + t;
    int v = (i < L) ? in[i] : 0;
    sh[t] = v;
    __syncthreads();
    for (int off = 1; off < 1024; off <<= 1) {
        int tv = (t >= off) ? sh[t - off] : 0;
        __syncthreads();
        sh[t] += tv;
        __syncthreads();
    }
    if (i < L) excl[i] = sh[t] - v;
    if (t == 1023) bsums[blockIdx.x] = sh[1023];
}

// scan2+scan3 fused: each block redundantly computes its exclusive prefix of
// bsums (exact int sum) then adds it to its 1024-element slice.
__global__ __launch_bounds__(1024) void k_scan23(int* __restrict__ excl,
                                                 const int* __restrict__ bsums,
                                                 int L) {
    __shared__ int sh[1024];
    const int t = threadIdx.x;
    sh[t] = (t < (int)blockIdx.x) ? bsums[t] : 0;
    __syncthreads();
    for (int off = 512; off > 0; off >>= 1) {
        if (t < off) sh[t] += sh[t + off];
        __syncthreads();
    }
    const int ofs = sh[0];
    int i = blockIdx.x * 1024 + t;
    if (i < L) excl[i] += ofs;
}

// ------------------------- launch P: partition + pack(W01*Q) + cvec
#define PBT 4096
__global__ __launch_bounds__(256) void kP(const int* __restrict__ src,
                                          const int* __restrict__ dst,
                                          const int* __restrict__ T2,
                                          unsigned* __restrict__ eb,
                                          int E, int NB, int chunk,
                                          const float* __restrict__ W01,
                                          const float* __restrict__ Q,
                                          const float* __restrict__ W1,
                                          const float* __restrict__ b0,
                                          const float* __restrict__ b1,
                                          const float* __restrict__ b2,
                                          const float* __restrict__ blin,
                                          const float* __restrict__ Wl,
                                          _Float16* __restrict__ wp,
                                          float* __restrict__ cv) {
    __shared__ int hist[512], lexc[512], pos[512], wpos[512];
    __shared__ unsigned sorted[PBT];
    __shared__ float Bs[128 * 64];
    __shared__ float As[4 * 128];
    __shared__ float t0s[128];
    __shared__ int nzf;
    const int t = threadIdx.x;
    const int b = blockIdx.x;
    if (b < 256) {
        const int blk = b;
        const int lo = blk * chunk, hi = min(E, lo + chunk);
        for (int i = t; i < NB; i += 256) wpos[i] = T2[i * 256 + blk];
        __syncthreads();
        for (int tlo = lo; tlo < hi; tlo += PBT) {
            const int thi = min(hi, tlo + PBT);
            const int sz = thi - tlo;
            for (int i = t; i < 512; i += 256) hist[i] = 0;
            __syncthreads();
            for (int e = tlo + t; e < thi; e += 256)
                atomicAdd(&hist[dst[e] >> 7], 1);
            __syncthreads();
            const int i0 = t, i1 = t + 256;
            const int o0 = hist[i0], o1 = hist[i1];
            for (int off = 1; off < 512; off <<= 1) {
                int v0 = (i0 >= off) ? hist[i0 - off] : 0;
                int v1 = (i1 >= off) ? hist[i1 - off] : 0;
                __syncthreads();
                hist[i0] += v0;
                hist[i1] += v1;
                __syncthreads();
            }
            lexc[i0] = hist[i0] - o0; pos[i0] = hist[i0] - o0;
            lexc[i1] = hist[i1] - o1; pos[i1] = hist[i1] - o1;
            __syncthreads();
            for (int e = tlo + t; e < thi; e += 256) {
                int d = dst[e];
                int p = atomicAdd(&pos[d >> 7], 1);
                sorted[p] = ((unsigned)d << 16) | (unsigned)src[e];
            }
            __syncthreads();
            for (int i = t; i < sz; i += 256) {
                unsigned x = sorted[i];
                int bb = (int)(x >> 23);
                eb[wpos[bb] + (i - lexc[bb])] = x;
            }
            __syncthreads();
            wpos[i0] += o0;
            wpos[i1] += o1;
            __syncthreads();
        }
    } else if (b < 320) {
        mm2v_dev(W01, Q, 64, 0, nullptr, 0, 0, wp, 1, b - 256, t, Bs, As);
    } else {
        // cvec: c0 = b0'(W1 Q) via t0 = W1'b0; c1 = b1'Q; c2 = b2'Wl + blin
        if (t == 0) nzf = 0;
        if (t < 128) {
            float s = 0.f;
            for (int j = 0; j < 128; ++j)
                s = fmaf(b0[j], W1[(size_t)j * 128 + t], s);
            t0s[t] = s;
        }
        __syncthreads();
        const int v = t >> 6;
        const int n = t & 63;
        if (v < 3) {
            float a0 = 0.f, a1 = 0.f, a2 = 0.f, a3 = 0.f;
            const float* bb = (v == 0) ? t0s : (v == 1) ? b1 : b2;
            const float* M = (v == 2) ? Wl : Q;
#pragma unroll
            for (int k = 0; k < 128; k += 4) {
                a0 = fmaf(bb[k + 0], M[(k + 0) * 64 + n], a0);
                a1 = fmaf(bb[k + 1], M[(k + 1) * 64 + n], a1);
                a2 = fmaf(bb[k + 2], M[(k + 2) * 64 + n], a2);
                a3 = fmaf(bb[k + 3], M[(k + 3) * 64 + n], a3);
            }
            float c = (a0 + a1) + (a2 + a3);
            if (v == 2) c += blin[n];
            cv[v * 64 + n] = c;
            if (v < 2 && c != 0.f) atomicOr(&nzf, 1);
        }
        __syncthreads();
        if (t == 0) cv[192] = nzf ? 1.f : 0.f;
    }
}

// ------------------------------------------------------- graph build, pass C
#define PCT 6144
__global__ __launch_bounds__(256) void k_build(const unsigned* __restrict__ eb,
                                               const int* __restrict__ T2,
                                               unsigned short* __restrict__ csr,
                                               int* __restrict__ rofs,
                                               float* __restrict__ dinv,
                                               int N, int E, int NB) {
    __shared__ int hist[128], lofs[128], pos[128];
    __shared__ unsigned short ssrc[PCT];
    const int t = threadIdx.x;
    const int b = blockIdx.x;
    const int glo = T2[b * 256];
    const int ghi = (b + 1 < NB) ? T2[(b + 1) * 256] : E;
    const int sz = ghi - glo;
    if (t < 128) hist[t] = 0;
    __syncthreads();
    for (int i = t; i < sz; i += 256)
        atomicAdd(&hist[(eb[glo + i] >> 16) & 127], 1);
    __syncthreads();
    const int o = (t < 128) ? hist[t] : 0;
    for (int off = 1; off < 128; off <<= 1) {
        int v = (t < 128 && t >= off) ? hist[t - off] : 0;
        __syncthreads();
        if (t < 128) hist[t] += v;
        __syncthreads();
    }
    if (t < 128) {
        int ex = hist[t] - o;
        lofs[t] = ex;
        pos[t] = ex;
        int d = b * 128 + t;
        if (d < N) {
            rofs[d] = glo + ex;
            dinv[d] = rsqrtf((float)(o + 1));
        }
    }
    __syncthreads();
    if (sz <= PCT) {
        for (int i = t; i < sz; i += 256) {
            unsigned x = eb[glo + i];
            int p = atomicAdd(&pos[(x >> 16) & 127], 1);
            ssrc[p] = (unsigned short)(x & 0xFFFFu);
        }
        __syncthreads();
        for (int i = t; i < sz; i += 256) csr[glo + i] = ssrc[i];
    } else {
        for (int i = t; i < sz; i += 256) {
            unsigned x = eb[glo + i];
            int p = atomicAdd(&pos[(x >> 16) & 127], 1);
            csr[glo + p] = (unsigned short)(x & 0xFFFFu);
        }
    }
    if (b == 0 && t == 0) rofs[N] = E;
}

// -------------------------------------------------------------------- GEMM
// 96-row block tile, 4 waves in 2x2 (wave: 48 rows x 32 cols).
// A staged in LDS (XOR-swizzled frag order), KB=128 per stage.
// B frags read directly from pre-packed global wp (L2-resident, coalesced).
template <int K, int M>
__global__ __launch_bounds__(256, 4) void k_gemm(const void* __restrict__ Av,
                                                 const _Float16* __restrict__ Wp,
                                                 const float* __restrict__ sc,
                                                 _Float16* __restrict__ out,
                                                 int N) {
    constexpr int KB = (K > 128) ? 128 : K;
    constexpr int NQ = K / KB;
    constexpr int NK = KB / 32;
    constexpr int KG = KB / 8;
    constexpr int CT = M / 32;
    constexpr int RT = 3;
    __shared__ _Float16 As[96 * KB];
    const int tid = threadIdx.x;
    const int lane = tid & 63;
    const int wave = tid >> 6;
    const int wrow = wave >> 1;
    const int wcol = wave & 1;
    const int R0 = blockIdx.x * 96;

    f32x4 acc[RT][CT];
#pragma unroll
    for (int rt = 0; rt < RT; ++rt)
#pragma unroll
        for (int ct = 0; ct < CT; ++ct) acc[rt][ct] = (f32x4){0.f, 0.f, 0.f, 0.f};

    for (int q = 0; q < NQ; ++q) {
        if (q) __syncthreads();
        {
            const float* A = (const float*)Av;
#pragma unroll
            for (int it = 0; it < (96 * KB) / (4 * 256); ++it) {
                int idx = tid + it * 256;
                int r = idx >> 5;
                int f4 = idx & 31;
                float4 g = {0.f, 0.f, 0.f, 0.f};
                if (R0 + r < N) g = *(const float4*)&A[(size_t)(R0 + r) * K + q * KB + f4 * 4];
                int kg = f4 >> 1, sub = f4 & 1;
                f16x4 h;
                h[0] = (_Float16)g.x; h[1] = (_Float16)g.y;
                h[2] = (_Float16)g.z; h[3] = (_Float16)g.w;
                *(f16x4*)&As[(r >> 4) * (KG * 128) + kg * 128 + (((r & 15) ^ kg) * 8) + sub * 4] = h;
            }
        }
        __syncthreads();
#pragma unroll
        for (int qq = 0; qq < NK; ++qq) {
            const int kk = q * NK + qq;
            const int kgq = qq * 4 + (lane >> 4);
            f16x8 af[RT], bf[CT];
#pragma unroll
            for (int ct = 0; ct < CT; ++ct) {
                int t = wcol * CT + ct;
                bf[ct] = *(const f16x8*)&Wp[((size_t)(t * (K / 32) + kk) * 64 + lane) * 8];
            }
#pragma unroll
            for (int rt = 0; rt < RT; ++rt) {
                int tr = wrow * RT + rt;
                af[rt] = *(const f16x8*)&As[tr * (KG * 128) + kgq * 128 + (((lane & 15) ^ kgq) * 8)];
            }
#pragma unroll
            for (int rt = 0; rt < RT; ++rt)
#pragma unroll
                for (int ct = 0; ct < CT; ++ct)
                    acc[rt][ct] = __builtin_amdgcn_mfma_f32_16x16x32_f16(af[rt], bf[ct], acc[rt][ct], 0, 0, 0);
        }
    }

    const int quad = lane >> 4;
#pragma unroll
    for (int rt = 0; rt < RT; ++rt)
#pragma unroll
        for (int reg = 0; reg < 4; ++reg) {
            int r = R0 + wrow * 48 + rt * 16 + quad * 4 + reg;
            if (r < N) {
                float s = sc[r];
#pragma unroll
                for (int ct = 0; ct < CT; ++ct) {
                    int c = wcol * (CT * 16) + ct * 16 + (lane & 15);
                    out[(size_t)r * M + c] = (_Float16)(acc[rt][ct][reg] * s);
                }
            }
        }
}

// ----------------------------------------------------- 64-wide aggregation
// One wave per dst row: 8 edge slots x 8 feature lanes (16 B/lane, 8 lanes =
// one 128 B row = ONE cache line per edge). 4 batched independent gathers
// (32 edges) in flight per wave.
// FIN=0: out = dinv^2 * sum.  FIN=1: Z = dinv*sum + bias terms, block max.
// UP=1: tail blocks compute u1/w1; UP=2: tail blocks compute u2.
template <int FIN, int UP>
__global__ __launch_bounds__(256) void k_agg64(const _Float16* __restrict__ tmp,
                                               const float* __restrict__ dinv,
                                               const int* __restrict__ rofs,
                                               const unsigned short* __restrict__ csr,
                                               const float* __restrict__ cv,
                                               float* __restrict__ u1,
                                               float* __restrict__ w1,
                                               float* __restrict__ u2,
                                               _Float16* __restrict__ out,
                                               float* __restrict__ bmax, int N) {
    __shared__ unsigned smax[64];
    const int tid = threadIdx.x;
    const int nbAg = (N + 3) / 4;
    const int vb = blockIdx.x;
    if (UP && vb >= nbAg) {
        // u-phase tail blocks (gated: zero-fill when biases are all zero)
        int d = (vb - nbAg) * 256 + tid;
        if (d >= N) return;
        if (UP == 1) {
            if (cv[192] == 0.f) { u1[d] = 0.f; w1[d] = 0.f; return; }
            float s = 0.f;
            const int beg = rofs[d], end = rofs[d + 1];
            for (int e = beg; e < end; ++e) s += dinv[csr[e]];
            float di = dinv[d];
            float u = di * (s + di);
            u1[d] = u;
            w1[d] = di * u;
        } else {
            if (cv[192] == 0.f) { u2[d] = 0.f; return; }
            float s = 0.f;
            const int beg = rofs[d], end = rofs[d + 1];
            for (int e = beg; e < end; ++e) s += w1[csr[e]];
            u2[d] = dinv[d] * (s + w1[d]);
        }
        return;
    }
    const int lane = tid & 63;
    const int wave = tid >> 6;
    const int d = vb * 4 + wave;
    const int eh = lane >> 3;
    const int fl = lane & 7;
    if (FIN) {
        if (tid < 64) smax[tid] = ENC_NEG_INF;
        __syncthreads();
    }
    if (d < N) {
        const int beg = rofs[d], end = rofs[d + 1];
        float a[8];
#pragma unroll
        for (int j = 0; j < 8; ++j) a[j] = 0.f;
        f16x8 vd;
        if (eh == 7) vd = *(const f16x8*)&tmp[(size_t)d * 64 + fl * 8];
        for (int base = beg; base < end; base += 32) {
            f16x8 v[4];
            unsigned msk = 0;
#pragma unroll
            for (int i = 0; i < 4; ++i) {
                int idx = base + 8 * i + eh;
                if (idx < end) {
                    int s = csr[idx];
                    v[i] = *(const f16x8*)&tmp[(size_t)s * 64 + fl * 8];
                    msk |= 1u << i;
                }
            }
#pragma unroll
            for (int i = 0; i < 4; ++i)
                if (msk & (1u << i)) {
#pragma unroll
                    for (int j = 0; j < 8; ++j) a[j] += (float)v[i][j];
                }
        }
        if (eh == 7) {
#pragma unroll
            for (int j = 0; j < 8; ++j) a[j] += (float)vd[j];
        }
#pragma unroll
        for (int j = 0; j < 8; ++j) {
            a[j] += __shfl_xor(a[j], 8, 64);
            a[j] += __shfl_xor(a[j], 16, 64);
            a[j] += __shfl_xor(a[j], 32, 64);
        }
        if (FIN == 0) {
            if (eh == 0) {
                float di = dinv[d];
                float s2 = di * di;
                f16x8 o;
#pragma unroll
                for (int j = 0; j < 8; ++j) o[j] = (_Float16)(a[j] * s2);
                *(f16x8*)&out[(size_t)d * 64 + fl * 8] = o;
            }
        } else {
            if (eh == 0) {
                float di = dinv[d];
                float v1 = u1[d], v2 = u2[d];
#pragma unroll
                for (int j = 0; j < 8; ++j) {
                    int f = fl * 8 + j;
                    float z = fmaf(di, a[j],
                              fmaf(v2, cv[f], fmaf(v1, cv[64 + f], cv[128 + f])));
                    atomicMax(&smax[f], enc_f32(z));
                }
            }
        }
    }
    if (FIN) {
        __syncthreads();
        if (tid < 64) bmax[(size_t)blockIdx.x * 64 + tid] = dec_f32(smax[tid]);
    }
}

// --------------------------------------------------------- final max pool
__global__ __launch_bounds__(256) void k_pool(const float* __restrict__ bmax,
                                              float* __restrict__ out, int nb) {
    __shared__ float sm[4];
    const int f = blockIdx.x;
    float m = -INFINITY;
    for (int b = threadIdx.x; b < nb; b += 256)
        m = fmaxf(m, bmax[(size_t)b * 64 + f]);
#pragma unroll
    for (int off = 1; off < 64; off <<= 1) m = fmaxf(m, __shfl_xor(m, off, 64));
    if ((threadIdx.x & 63) == 0) sm[threadIdx.x >> 6] = m;
    __syncthreads();
    if (threadIdx.x == 0)
        out[f] = fmaxf(fmaxf(sm[0], sm[1]), fmaxf(sm[2], sm[3]));
}

// ---------------------------------------------------------------------------
extern "C" void kernel_launch(void* const* d_in, const int* in_sizes, int n_in,
                              void* d_out, int out_size, void* d_ws, size_t ws_size,
                              hipStream_t stream) {
    const float* x    = (const float*)d_in[0];
    const int*   ei   = (const int*)d_in[1];  // [2,E]: row0=src, row1=dst
    const float* W0   = (const float*)d_in[3];
    const float* b0   = (const float*)d_in[4];
    const float* W1   = (const float*)d_in[5];
    const float* b1   = (const float*)d_in[6];
    const float* W2   = (const float*)d_in[7];
    const float* b2   = (const float*)d_in[8];
    const float* Wlin = (const float*)d_in[9];
    const float* blin = (const float*)d_in[10];
    float* out = (float*)d_out;

    const int N = in_sizes[2];
    const int E = in_sizes[1] / 2;
    const int* src = ei;
    const int* dst = ei + E;

    size_t off = 0;
    auto carve = [&](size_t bytes) {
        void* p = (char*)d_ws + off;
        off += (bytes + 255) & ~(size_t)255;
        return p;
    };
    const int NB    = (N + 127) / 128;
    const int L     = NB * 256;
    const int chunk = (E + 255) / 256;
    const int nbAg  = (N + 3) / 4;
    const int nbU   = (N + 255) / 256;

    float*          dinv = (float*)carve((size_t)N * 4);
    int*            rofs = (int*)carve((size_t)(N + 1) * 4);
    int*            T    = (int*)carve((size_t)L * 4);
    int*            T2   = (int*)carve((size_t)L * 4);
    int*            bsums = (int*)carve(1024 * 4);
    unsigned*       eb   = (unsigned*)carve((size_t)E * 4);
    unsigned short* csr  = (unsigned short*)carve((size_t)E * 2);
    _Float16*       tmpY = (_Float16*)carve((size_t)N * 64 * 2);
    _Float16*       tmpZ = (_Float16*)carve((size_t)N * 64 * 2);
    float*          u1   = (float*)carve((size_t)N * 4);
    float*          w1   = (float*)carve((size_t)N * 4);
    float*          u2   = (float*)carve((size_t)N * 4);
    float*          bmax = (float*)carve((size_t)nbAg * 64 * 4);
    float*          Q    = (float*)carve(128 * 64 * 4);
    float*          W01  = (float*)carve(256 * 128 * 4);
    float*          cv   = (float*)carve(256 * 4);
    _Float16*       wp   = (_Float16*)carve(256 * 64 * 2);
    (void)ws_size; (void)n_in; (void)out_size;

    const int nbG = (N + 95) / 96;
    const int nbS = (L + 1023) / 1024;

    // 1: W01 = W0*W1 (2 halves) || Q = W2*Wlin || hist
    kA<<<416, 256, 0, stream>>>(W0, W1, W2, Wlin, dst, T, W01, Q, E, NB, chunk);
    // 2-3: scan
    k_scan1<<<nbS, 1024, 0, stream>>>(T, T2, bsums, L);
    k_scan23<<<nbS, 1024, 0, stream>>>(T2, bsums, L);
    // 4: partition || wp = pack(W01*Q) || cvec
    kP<<<321, 256, 0, stream>>>(src, dst, T2, eb, E, NB, chunk,
                                W01, Q, W1, b0, b1, b2, blin, Wlin, wp, cv);
    // 5: per-bucket counting sort -> csr, rofs, dinv
    k_build<<<NB, 256, 0, stream>>>(eb, T2, csr, rofs, dinv, N, E, NB);
    // 6: Y = dinv .* (X * W0123)
    k_gemm<256, 64><<<nbG, 256, 0, stream>>>(x, wp, dinv, tmpY, N);
    // 7: hop1 (Y->Z) || u1
    k_agg64<0, 1><<<nbAg + nbU, 256, 0, stream>>>(tmpY, dinv, rofs, csr, cv,
                                                  u1, w1, u2, tmpZ, nullptr, N);
    // 8: hop2 (Z->Y) || u2
    k_agg64<0, 2><<<nbAg + nbU, 256, 0, stream>>>(tmpZ, dinv, rofs, csr, cv,
                                                  u1, w1, u2, tmpY, nullptr, N);
    // 9: hop3 + bias + block max
    k_agg64<1, 0><<<nbAg, 256, 0, stream>>>(tmpY, dinv, rofs, csr, cv,
                                            u1, w1, u2, nullptr, bmax, N);
    // 10: final pool
    k_pool<<<64, 256, 0, stream>>>(bmax, out, nbAg);
}

// Round 9
// 237.272 us; speedup vs baseline: 5.6390x; 1.0372x over previous
//
#include <hip/hip_runtime.h>
#include <math.h>

// ---------------------------------------------------------------------------
// GCN forward: 3x GCNConv (sym-norm, self-loops) + linear + global max pool.
// N=50000, E=800000, F=256, H=128, O=64. fp32 in/out, fp16 intermediates.
//
// R18 = R17 (246us; reassociated Z = A^3 X (W0W1W2Wlin) + bias terms, 10
// launches) with the agg inner loop rewritten for the measured bottleneck:
// edge rate is ~20G edges/s across 1-line and 2-line layouts -> per-edge
// VALU/issue-bound (16 cvt+add per lane per edge), NOT line-request-bound.
// New k_agg64: (a) 4-edge groups tree-summed in f16 (v_pk_add_f16) with one
// f32 accumulate per group (~7 VALU/edge, 2.3x cut); (b) 2 rows per wave
// (8 gathers in flight, half the loop overhead).
// ---------------------------------------------------------------------------

typedef __attribute__((ext_vector_type(8))) _Float16 f16x8;
typedef __attribute__((ext_vector_type(4))) _Float16 f16x4;
typedef __attribute__((ext_vector_type(4))) float f32x4;

__device__ __forceinline__ unsigned enc_f32(float f) {
    unsigned u = __float_as_uint(f);
    return (u & 0x80000000u) ? ~u : (u | 0x80000000u);
}
__device__ __forceinline__ float dec_f32(unsigned e) {
    return (e & 0x80000000u) ? __uint_as_float(e & 0x7fffffffu)
                             : __uint_as_float(~e);
}
#define ENC_NEG_INF 0x007FFFFFu  // enc(-inf)

// --------------------------------------------- tiny latency-optimal GEMM tile
__device__ __forceinline__ void mm2v_dev(const float* __restrict__ A,
                                         const float* __restrict__ B,
                                         int ldb, int bcol0,
                                         float* __restrict__ C,
                                         int ldc, int ccol0,
                                         _Float16* __restrict__ Wp, int pack,
                                         int vb, int tid,
                                         float* __restrict__ Bs,
                                         float* __restrict__ As) {
    const int r0 = vb * 4;
#pragma unroll
    for (int it = 0; it < 8; ++it) {
        int f = tid + it * 256;          // 2048 float4 slots: row = f>>4
        int row = f >> 4, c4 = (f & 15) * 4;
        *(float4*)&Bs[row * 64 + c4] = *(const float4*)&B[(size_t)row * ldb + bcol0 + c4];
    }
    if (tid < 128)
        *(float4*)&As[tid * 4] = *(const float4*)&A[(size_t)r0 * 128 + tid * 4];
    __syncthreads();
    const int n = tid & 63;
    const int rh = tid >> 6;
    float a0 = 0.f, a1 = 0.f, a2 = 0.f, a3 = 0.f;
#pragma unroll
    for (int k = 0; k < 128; k += 4) {
        a0 = fmaf(As[rh * 128 + k + 0], Bs[(k + 0) * 64 + n], a0);
        a1 = fmaf(As[rh * 128 + k + 1], Bs[(k + 1) * 64 + n], a1);
        a2 = fmaf(As[rh * 128 + k + 2], Bs[(k + 2) * 64 + n], a2);
        a3 = fmaf(As[rh * 128 + k + 3], Bs[(k + 3) * 64 + n], a3);
    }
    float acc = (a0 + a1) + (a2 + a3);
    const int kk = r0 + rh;
    if (pack) {
        int j = kk & 7;
        int l = ((kk >> 3) & 3) * 16 + (n & 15);
        int q = kk >> 5;
        int c = n >> 4;
        Wp[((size_t)(c * 8 + q) * 64 + l) * 8 + j] = (_Float16)acc;
    } else {
        C[(size_t)kk * ldc + ccol0 + n] = acc;
    }
}

// ------------------------------------- launch A: W01 halves + Q + histogram
__global__ __launch_bounds__(256) void kA(const float* __restrict__ W0,
                                          const float* __restrict__ W1,
                                          const float* __restrict__ W2,
                                          const float* __restrict__ Wl,
                                          const int* __restrict__ dst,
                                          int* __restrict__ T,
                                          float* __restrict__ W01,
                                          float* __restrict__ Q,
                                          int E, int NB, int chunk) {
    __shared__ float Bs[128 * 64];
    __shared__ float As[4 * 128];
    __shared__ int hist[512];
    const int b = blockIdx.x;
    const int tid = threadIdx.x;
    if (b < 64) {
        mm2v_dev(W0, W1, 128, 0, W01, 128, 0, nullptr, 0, b, tid, Bs, As);
    } else if (b < 128) {
        mm2v_dev(W0, W1, 128, 64, W01, 128, 64, nullptr, 0, b - 64, tid, Bs, As);
    } else if (b < 160) {
        mm2v_dev(W2, Wl, 64, 0, Q, 64, 0, nullptr, 0, b - 128, tid, Bs, As);
    } else {
        const int blk = b - 160;
        for (int i = tid; i < 512; i += 256) hist[i] = 0;
        __syncthreads();
        const int lo = blk * chunk, hi = min(E, lo + chunk);
        for (int e = lo + tid; e < hi; e += 256)
            atomicAdd(&hist[dst[e] >> 7], 1);
        __syncthreads();
        for (int bk = tid; bk < NB; bk += 256)
            T[bk * 256 + blk] = hist[bk];
    }
}

// ------------------------------------------------------------- scan kernels
__global__ __launch_bounds__(1024) void k_scan1(const int* __restrict__ in,
                                                int* __restrict__ excl,
                                                int* __restrict__ bsums, int L) {
    __shared__ int sh[1024];
    int t = threadIdx.x;
    int i = blockIdx.x * 1024 + t;
    int v = (i < L) ? in[i] : 0;
    sh[t] = v;
    __syncthreads();
    for (int off = 1; off < 1024; off <<= 1) {
        int tv = (t >= off) ? sh[t - off] : 0;
        __syncthreads();
        sh[t] += tv;
        __syncthreads();
    }
    if (i < L) excl[i] = sh[t] - v;
    if (t == 1023) bsums[blockIdx.x] = sh[1023];
}

// scan2+scan3 fused: each block redundantly computes its exclusive prefix of
// bsums then adds it to its 1024-element slice.
__global__ __launch_bounds__(1024) void k_scan23(int* __restrict__ excl,
                                                 const int* __restrict__ bsums,
                                                 int L) {
    __shared__ int sh[1024];
    const int t = threadIdx.x;
    sh[t] = (t < (int)blockIdx.x) ? bsums[t] : 0;
    __syncthreads();
    for (int off = 512; off > 0; off >>= 1) {
        if (t < off) sh[t] += sh[t + off];
        __syncthreads();
    }
    const int ofs = sh[0];
    int i = blockIdx.x * 1024 + t;
    if (i < L) excl[i] += ofs;
}

// ------------------------- launch P: partition + pack(W01*Q) + cvec
#define PBT 4096
__global__ __launch_bounds__(256) void kP(const int* __restrict__ src,
                                          const int* __restrict__ dst,
                                          const int* __restrict__ T2,
                                          unsigned* __restrict__ eb,
                                          int E, int NB, int chunk,
                                          const float* __restrict__ W01,
                                          const float* __restrict__ Q,
                                          const float* __restrict__ W1,
                                          const float* __restrict__ b0,
                                          const float* __restrict__ b1,
                                          const float* __restrict__ b2,
                                          const float* __restrict__ blin,
                                          const float* __restrict__ Wl,
                                          _Float16* __restrict__ wp,
                                          float* __restrict__ cv) {
    __shared__ int hist[512], lexc[512], pos[512], wpos[512];
    __shared__ unsigned sorted[PBT];
    __shared__ float Bs[128 * 64];
    __shared__ float As[4 * 128];
    __shared__ float t0s[128];
    __shared__ int nzf;
    const int t = threadIdx.x;
    const int b = blockIdx.x;
    if (b < 256) {
        const int blk = b;
        const int lo = blk * chunk, hi = min(E, lo + chunk);
        for (int i = t; i < NB; i += 256) wpos[i] = T2[i * 256 + blk];
        __syncthreads();
        for (int tlo = lo; tlo < hi; tlo += PBT) {
            const int thi = min(hi, tlo + PBT);
            const int sz = thi - tlo;
            for (int i = t; i < 512; i += 256) hist[i] = 0;
            __syncthreads();
            for (int e = tlo + t; e < thi; e += 256)
                atomicAdd(&hist[dst[e] >> 7], 1);
            __syncthreads();
            const int i0 = t, i1 = t + 256;
            const int o0 = hist[i0], o1 = hist[i1];
            for (int off = 1; off < 512; off <<= 1) {
                int v0 = (i0 >= off) ? hist[i0 - off] : 0;
                int v1 = (i1 >= off) ? hist[i1 - off] : 0;
                __syncthreads();
                hist[i0] += v0;
                hist[i1] += v1;
                __syncthreads();
            }
            lexc[i0] = hist[i0] - o0; pos[i0] = hist[i0] - o0;
            lexc[i1] = hist[i1] - o1; pos[i1] = hist[i1] - o1;
            __syncthreads();
            for (int e = tlo + t; e < thi; e += 256) {
                int d = dst[e];
                int p = atomicAdd(&pos[d >> 7], 1);
                sorted[p] = ((unsigned)d << 16) | (unsigned)src[e];
            }
            __syncthreads();
            for (int i = t; i < sz; i += 256) {
                unsigned x = sorted[i];
                int bb = (int)(x >> 23);
                eb[wpos[bb] + (i - lexc[bb])] = x;
            }
            __syncthreads();
            wpos[i0] += o0;
            wpos[i1] += o1;
            __syncthreads();
        }
    } else if (b < 320) {
        mm2v_dev(W01, Q, 64, 0, nullptr, 0, 0, wp, 1, b - 256, t, Bs, As);
    } else {
        // cvec: c0 = b0'(W1 Q) via t0 = W1'b0; c1 = b1'Q; c2 = b2'Wl + blin
        if (t == 0) nzf = 0;
        if (t < 128) {
            float s = 0.f;
            for (int j = 0; j < 128; ++j)
                s = fmaf(b0[j], W1[(size_t)j * 128 + t], s);
            t0s[t] = s;
        }
        __syncthreads();
        const int v = t >> 6;
        const int n = t & 63;
        if (v < 3) {
            float a0 = 0.f, a1 = 0.f, a2 = 0.f, a3 = 0.f;
            const float* bb = (v == 0) ? t0s : (v == 1) ? b1 : b2;
            const float* M = (v == 2) ? Wl : Q;
#pragma unroll
            for (int k = 0; k < 128; k += 4) {
                a0 = fmaf(bb[k + 0], M[(k + 0) * 64 + n], a0);
                a1 = fmaf(bb[k + 1], M[(k + 1) * 64 + n], a1);
                a2 = fmaf(bb[k + 2], M[(k + 2) * 64 + n], a2);
                a3 = fmaf(bb[k + 3], M[(k + 3) * 64 + n], a3);
            }
            float c = (a0 + a1) + (a2 + a3);
            if (v == 2) c += blin[n];
            cv[v * 64 + n] = c;
            if (v < 2 && c != 0.f) atomicOr(&nzf, 1);
        }
        __syncthreads();
        if (t == 0) cv[192] = nzf ? 1.f : 0.f;
    }
}

// ------------------------------------------------------- graph build, pass C
#define PCT 6144
__global__ __launch_bounds__(256) void k_build(const unsigned* __restrict__ eb,
                                               const int* __restrict__ T2,
                                               unsigned short* __restrict__ csr,
                                               int* __restrict__ rofs,
                                               float* __restrict__ dinv,
                                               int N, int E, int NB) {
    __shared__ int hist[128], lofs[128], pos[128];
    __shared__ unsigned short ssrc[PCT];
    const int t = threadIdx.x;
    const int b = blockIdx.x;
    const int glo = T2[b * 256];
    const int ghi = (b + 1 < NB) ? T2[(b + 1) * 256] : E;
    const int sz = ghi - glo;
    if (t < 128) hist[t] = 0;
    __syncthreads();
    for (int i = t; i < sz; i += 256)
        atomicAdd(&hist[(eb[glo + i] >> 16) & 127], 1);
    __syncthreads();
    const int o = (t < 128) ? hist[t] : 0;
    for (int off = 1; off < 128; off <<= 1) {
        int v = (t < 128 && t >= off) ? hist[t - off] : 0;
        __syncthreads();
        if (t < 128) hist[t] += v;
        __syncthreads();
    }
    if (t < 128) {
        int ex = hist[t] - o;
        lofs[t] = ex;
        pos[t] = ex;
        int d = b * 128 + t;
        if (d < N) {
            rofs[d] = glo + ex;
            dinv[d] = rsqrtf((float)(o + 1));
        }
    }
    __syncthreads();
    if (sz <= PCT) {
        for (int i = t; i < sz; i += 256) {
            unsigned x = eb[glo + i];
            int p = atomicAdd(&pos[(x >> 16) & 127], 1);
            ssrc[p] = (unsigned short)(x & 0xFFFFu);
        }
        __syncthreads();
        for (int i = t; i < sz; i += 256) csr[glo + i] = ssrc[i];
    } else {
        for (int i = t; i < sz; i += 256) {
            unsigned x = eb[glo + i];
            int p = atomicAdd(&pos[(x >> 16) & 127], 1);
            csr[glo + p] = (unsigned short)(x & 0xFFFFu);
        }
    }
    if (b == 0 && t == 0) rofs[N] = E;
}

// -------------------------------------------------------------------- GEMM
template <int K, int M>
__global__ __launch_bounds__(256, 4) void k_gemm(const void* __restrict__ Av,
                                                 const _Float16* __restrict__ Wp,
                                                 const float* __restrict__ sc,
                                                 _Float16* __restrict__ out,
                                                 int N) {
    constexpr int KB = (K > 128) ? 128 : K;
    constexpr int NQ = K / KB;
    constexpr int NK = KB / 32;
    constexpr int KG = KB / 8;
    constexpr int CT = M / 32;
    constexpr int RT = 3;
    __shared__ _Float16 As[96 * KB];
    const int tid = threadIdx.x;
    const int lane = tid & 63;
    const int wave = tid >> 6;
    const int wrow = wave >> 1;
    const int wcol = wave & 1;
    const int R0 = blockIdx.x * 96;

    f32x4 acc[RT][CT];
#pragma unroll
    for (int rt = 0; rt < RT; ++rt)
#pragma unroll
        for (int ct = 0; ct < CT; ++ct) acc[rt][ct] = (f32x4){0.f, 0.f, 0.f, 0.f};

    for (int q = 0; q < NQ; ++q) {
        if (q) __syncthreads();
        {
            const float* A = (const float*)Av;
#pragma unroll
            for (int it = 0; it < (96 * KB) / (4 * 256); ++it) {
                int idx = tid + it * 256;
                int r = idx >> 5;
                int f4 = idx & 31;
                float4 g = {0.f, 0.f, 0.f, 0.f};
                if (R0 + r < N) g = *(const float4*)&A[(size_t)(R0 + r) * K + q * KB + f4 * 4];
                int kg = f4 >> 1, sub = f4 & 1;
                f16x4 h;
                h[0] = (_Float16)g.x; h[1] = (_Float16)g.y;
                h[2] = (_Float16)g.z; h[3] = (_Float16)g.w;
                *(f16x4*)&As[(r >> 4) * (KG * 128) + kg * 128 + (((r & 15) ^ kg) * 8) + sub * 4] = h;
            }
        }
        __syncthreads();
#pragma unroll
        for (int qq = 0; qq < NK; ++qq) {
            const int kk = q * NK + qq;
            const int kgq = qq * 4 + (lane >> 4);
            f16x8 af[RT], bf[CT];
#pragma unroll
            for (int ct = 0; ct < CT; ++ct) {
                int t = wcol * CT + ct;
                bf[ct] = *(const f16x8*)&Wp[((size_t)(t * (K / 32) + kk) * 64 + lane) * 8];
            }
#pragma unroll
            for (int rt = 0; rt < RT; ++rt) {
                int tr = wrow * RT + rt;
                af[rt] = *(const f16x8*)&As[tr * (KG * 128) + kgq * 128 + (((lane & 15) ^ kgq) * 8)];
            }
#pragma unroll
            for (int rt = 0; rt < RT; ++rt)
#pragma unroll
                for (int ct = 0; ct < CT; ++ct)
                    acc[rt][ct] = __builtin_amdgcn_mfma_f32_16x16x32_f16(af[rt], bf[ct], acc[rt][ct], 0, 0, 0);
        }
    }

    const int quad = lane >> 4;
#pragma unroll
    for (int rt = 0; rt < RT; ++rt)
#pragma unroll
        for (int reg = 0; reg < 4; ++reg) {
            int r = R0 + wrow * 48 + rt * 16 + quad * 4 + reg;
            if (r < N) {
                float s = sc[r];
#pragma unroll
                for (int ct = 0; ct < CT; ++ct) {
                    int c = wcol * (CT * 16) + ct * 16 + (lane & 15);
                    out[(size_t)r * M + c] = (_Float16)(acc[rt][ct][reg] * s);
                }
            }
        }
}

// ----------------------------------------------------- 64-wide aggregation
// 2 rows per wave (8 rows/block): 8 edge slots x 8 feature lanes per row,
// 8 gathers in flight/wave. 4-edge groups tree-summed in f16 (v_pk_add_f16)
// then ONE f32 accumulate per group: ~7 VALU/edge vs 16 (edge-rate-bound
// diagnosis). FIN=0: out = dinv^2*sum. FIN=1: Z = dinv*sum + bias terms,
// block max -> bmax. UP=1/2: tail blocks compute u1/u2 (bias-gated).
template <int FIN, int UP>
__global__ __launch_bounds__(256) void k_agg64(const _Float16* __restrict__ tmp,
                                               const float* __restrict__ dinv,
                                               const int* __restrict__ rofs,
                                               const unsigned short* __restrict__ csr,
                                               const float* __restrict__ cv,
                                               float* __restrict__ u1,
                                               float* __restrict__ w1,
                                               float* __restrict__ u2,
                                               _Float16* __restrict__ out,
                                               float* __restrict__ bmax, int N) {
    __shared__ unsigned smax[64];
    const int tid = threadIdx.x;
    const int nbAgg = (N + 7) / 8;
    const int vb = blockIdx.x;
    if (UP && vb >= nbAgg) {
        int d = (vb - nbAgg) * 256 + tid;
        if (d >= N) return;
        if (UP == 1) {
            if (cv[192] == 0.f) { u1[d] = 0.f; w1[d] = 0.f; return; }
            float s = 0.f;
            const int beg = rofs[d], end = rofs[d + 1];
            for (int e = beg; e < end; ++e) s += dinv[csr[e]];
            float di = dinv[d];
            float u = di * (s + di);
            u1[d] = u;
            w1[d] = di * u;
        } else {
            if (cv[192] == 0.f) { u2[d] = 0.f; return; }
            float s = 0.f;
            const int beg = rofs[d], end = rofs[d + 1];
            for (int e = beg; e < end; ++e) s += w1[csr[e]];
            u2[d] = dinv[d] * (s + w1[d]);
        }
        return;
    }
    const int lane = tid & 63;
    const int wave = tid >> 6;
    const int eh = lane >> 3;   // edge slot 0..7
    const int fl = lane & 7;    // feature octet 0..7
    const int d0 = vb * 8 + wave * 2;
    const int d1 = d0 + 1;
    const bool r0 = d0 < N;
    const bool r1 = d1 < N;
    if (FIN) {
        if (tid < 64) smax[tid] = ENC_NEG_INF;
        __syncthreads();
    }
    f16x8 z;
#pragma unroll
    for (int j = 0; j < 8; ++j) z[j] = (_Float16)0.f;

    float a0[8], a1[8];
#pragma unroll
    for (int j = 0; j < 8; ++j) { a0[j] = 0.f; a1[j] = 0.f; }

    int e0 = 0, n0 = 0, e1 = 0, n1 = 0;
    if (r0) { e0 = rofs[d0]; n0 = rofs[d0 + 1]; }
    if (r1) { e1 = rofs[d1]; n1 = rofs[d1 + 1]; }

    while ((r0 && e0 < n0) || (r1 && e1 < n1)) {
        f16x8 v0[4], v1[4];
#pragma unroll
        for (int i = 0; i < 4; ++i) {
            int i0 = e0 + 8 * i + eh;
            v0[i] = (r0 && i0 < n0)
                        ? *(const f16x8*)&tmp[(size_t)csr[i0] * 64 + fl * 8] : z;
            int i1 = e1 + 8 * i + eh;
            v1[i] = (r1 && i1 < n1)
                        ? *(const f16x8*)&tmp[(size_t)csr[i1] * 64 + fl * 8] : z;
        }
        f16x8 s0 = (v0[0] + v0[1]) + (v0[2] + v0[3]);
        f16x8 s1 = (v1[0] + v1[1]) + (v1[2] + v1[3]);
#pragma unroll
        for (int j = 0; j < 8; ++j) {
            a0[j] += (float)s0[j];
            a1[j] += (float)s1[j];
        }
        e0 += 32;
        e1 += 32;
    }
    // self-loops (f32 path)
    if (r0 && eh == 7) {
        f16x8 v = *(const f16x8*)&tmp[(size_t)d0 * 64 + fl * 8];
#pragma unroll
        for (int j = 0; j < 8; ++j) a0[j] += (float)v[j];
    }
    if (r1 && eh == 7) {
        f16x8 v = *(const f16x8*)&tmp[(size_t)d1 * 64 + fl * 8];
#pragma unroll
        for (int j = 0; j < 8; ++j) a1[j] += (float)v[j];
    }
#pragma unroll
    for (int j = 0; j < 8; ++j) {
        a0[j] += __shfl_xor(a0[j], 8, 64);
        a0[j] += __shfl_xor(a0[j], 16, 64);
        a0[j] += __shfl_xor(a0[j], 32, 64);
        a1[j] += __shfl_xor(a1[j], 8, 64);
        a1[j] += __shfl_xor(a1[j], 16, 64);
        a1[j] += __shfl_xor(a1[j], 32, 64);
    }
    if (eh == 0) {
        if (FIN == 0) {
            if (r0) {
                float di = dinv[d0];
                float s2 = di * di;
                f16x8 o;
#pragma unroll
                for (int j = 0; j < 8; ++j) o[j] = (_Float16)(a0[j] * s2);
                *(f16x8*)&out[(size_t)d0 * 64 + fl * 8] = o;
            }
            if (r1) {
                float di = dinv[d1];
                float s2 = di * di;
                f16x8 o;
#pragma unroll
                for (int j = 0; j < 8; ++j) o[j] = (_Float16)(a1[j] * s2);
                *(f16x8*)&out[(size_t)d1 * 64 + fl * 8] = o;
            }
        } else {
            if (r0) {
                float di = dinv[d0];
                float v1c = u1[d0], v2c = u2[d0];
#pragma unroll
                for (int j = 0; j < 8; ++j) {
                    int f = fl * 8 + j;
                    float zv = fmaf(di, a0[j],
                               fmaf(v2c, cv[f], fmaf(v1c, cv[64 + f], cv[128 + f])));
                    atomicMax(&smax[f], enc_f32(zv));
                }
            }
            if (r1) {
                float di = dinv[d1];
                float v1c = u1[d1], v2c = u2[d1];
#pragma unroll
                for (int j = 0; j < 8; ++j) {
                    int f = fl * 8 + j;
                    float zv = fmaf(di, a1[j],
                               fmaf(v2c, cv[f], fmaf(v1c, cv[64 + f], cv[128 + f])));
                    atomicMax(&smax[f], enc_f32(zv));
                }
            }
        }
    }
    if (FIN) {
        __syncthreads();
        if (tid < 64) bmax[(size_t)blockIdx.x * 64 + tid] = dec_f32(smax[tid]);
    }
}

// --------------------------------------------------------- final max pool
__global__ __launch_bounds__(256) void k_pool(const float* __restrict__ bmax,
                                              float* __restrict__ out, int nb) {
    __shared__ float sm[4];
    const int f = blockIdx.x;
    float m = -INFINITY;
    for (int b = threadIdx.x; b < nb; b += 256)
        m = fmaxf(m, bmax[(size_t)b * 64 + f]);
#pragma unroll
    for (int off = 1; off < 64; off <<= 1) m = fmaxf(m, __shfl_xor(m, off, 64));
    if ((threadIdx.x & 63) == 0) sm[threadIdx.x >> 6] = m;
    __syncthreads();
    if (threadIdx.x == 0)
        out[f] = fmaxf(fmaxf(sm[0], sm[1]), fmaxf(sm[2], sm[3]));
}

// ---------------------------------------------------------------------------
extern "C" void kernel_launch(void* const* d_in, const int* in_sizes, int n_in,
                              void* d_out, int out_size, void* d_ws, size_t ws_size,
                              hipStream_t stream) {
    const float* x    = (const float*)d_in[0];
    const int*   ei   = (const int*)d_in[1];  // [2,E]: row0=src, row1=dst
    const float* W0   = (const float*)d_in[3];
    const float* b0   = (const float*)d_in[4];
    const float* W1   = (const float*)d_in[5];
    const float* b1   = (const float*)d_in[6];
    const float* W2   = (const float*)d_in[7];
    const float* b2   = (const float*)d_in[8];
    const float* Wlin = (const float*)d_in[9];
    const float* blin = (const float*)d_in[10];
    float* out = (float*)d_out;

    const int N = in_sizes[2];
    const int E = in_sizes[1] / 2;
    const int* src = ei;
    const int* dst = ei + E;

    size_t off = 0;
    auto carve = [&](size_t bytes) {
        void* p = (char*)d_ws + off;
        off += (bytes + 255) & ~(size_t)255;
        return p;
    };
    const int NB    = (N + 127) / 128;
    const int L     = NB * 256;
    const int chunk = (E + 255) / 256;
    const int nbAgg = (N + 7) / 8;
    const int nbU   = (N + 255) / 256;

    float*          dinv = (float*)carve((size_t)N * 4);
    int*            rofs = (int*)carve((size_t)(N + 1) * 4);
    int*            T    = (int*)carve((size_t)L * 4);
    int*            T2   = (int*)carve((size_t)L * 4);
    int*            bsums = (int*)carve(1024 * 4);
    unsigned*       eb   = (unsigned*)carve((size_t)E * 4);
    unsigned short* csr  = (unsigned short*)carve((size_t)E * 2);
    _Float16*       tmpY = (_Float16*)carve((size_t)N * 64 * 2);
    _Float16*       tmpZ = (_Float16*)carve((size_t)N * 64 * 2);
    float*          u1   = (float*)carve((size_t)N * 4);
    float*          w1   = (float*)carve((size_t)N * 4);
    float*          u2   = (float*)carve((size_t)N * 4);
    float*          bmax = (float*)carve((size_t)nbAgg * 64 * 4);
    float*          Q    = (float*)carve(128 * 64 * 4);
    float*          W01  = (float*)carve(256 * 128 * 4);
    float*          cv   = (float*)carve(256 * 4);
    _Float16*       wp   = (_Float16*)carve(256 * 64 * 2);
    (void)ws_size; (void)n_in; (void)out_size;

    const int nbG = (N + 95) / 96;
    const int nbS = (L + 1023) / 1024;

    // 1: W01 = W0*W1 (2 halves) || Q = W2*Wlin || hist
    kA<<<416, 256, 0, stream>>>(W0, W1, W2, Wlin, dst, T, W01, Q, E, NB, chunk);
    // 2-3: scan
    k_scan1<<<nbS, 1024, 0, stream>>>(T, T2, bsums, L);
    k_scan23<<<nbS, 1024, 0, stream>>>(T2, bsums, L);
    // 4: partition || wp = pack(W01*Q) || cvec
    kP<<<321, 256, 0, stream>>>(src, dst, T2, eb, E, NB, chunk,
                                W01, Q, W1, b0, b1, b2, blin, Wlin, wp, cv);
    // 5: per-bucket counting sort -> csr, rofs, dinv
    k_build<<<NB, 256, 0, stream>>>(eb, T2, csr, rofs, dinv, N, E, NB);
    // 6: Y = dinv .* (X * W0123)
    k_gemm<256, 64><<<nbG, 256, 0, stream>>>(x, wp, dinv, tmpY, N);
    // 7: hop1 (Y->Z) || u1
    k_agg64<0, 1><<<nbAgg + nbU, 256, 0, stream>>>(tmpY, dinv, rofs, csr, cv,
                                                   u1, w1, u2, tmpZ, nullptr, N);
    // 8: hop2 (Z->Y) || u2
    k_agg64<0, 2><<<nbAgg + nbU, 256, 0, stream>>>(tmpZ, dinv, rofs, csr, cv,
                                                   u1, w1, u2, tmpY, nullptr, N);
    // 9: hop3 + bias + block max
    k_agg64<1, 0><<<nbAgg, 256, 0, stream>>>(tmpY, dinv, rofs, csr, cv,
                                             u1, w1, u2, nullptr, bmax, N);
    // 10: final pool
    k_pool<<<64, 256, 0, stream>>>(bmax, out, nbAgg);
}